// Round 10
// baseline (277.919 us; speedup 1.0000x reference)
//
#include <hip/hip_runtime.h>
#include <math.h>

#define CCH 256      // channels C
#define OCH 50       // output channels O
#define NPIX 16384   // H*W
#define BATCH 4
#define BO (BATCH*OCH)   // 200
#define NSPLIT2 256      // 64-pixel chunks
#define KC2 (NPIX/NSPLIT2)

typedef _Float16 f16x8 __attribute__((ext_vector_type(8)));
typedef float f32x4 __attribute__((ext_vector_type(4)));
typedef unsigned int uint;
typedef unsigned short ushort;

__device__ __forceinline__ void cvt_split(const float4 v0, const float4 v1,
                                          f16x8& h, f16x8& l) {
    float v[8] = {v0.x, v0.y, v0.z, v0.w, v1.x, v1.y, v1.z, v1.w};
#pragma unroll
    for (int j = 0; j < 8; ++j) {
        _Float16 hj = (_Float16)v[j];
        h[j] = hj;
        l[j] = (_Float16)(v[j] - (float)hj);
    }
}

__device__ __forceinline__ uint packhl(float v) {
    _Float16 h = (_Float16)v;
    _Float16 l = (_Float16)(v - (float)h);
    union { _Float16 f; ushort u; } H, L;
    H.f = h; L.f = l;
    return (uint)H.u | ((uint)L.u << 16);
}

// ---------- K0: split W_f [50,256] -> Wfh/Wfl [64,256] f16 planes, zero-padded ----------
__global__ void k0_split(const float* __restrict__ Wf, _Float16* __restrict__ Wfh,
                         _Float16* __restrict__ Wfl) {
    int i = blockIdx.x * 256 + threadIdx.x;   // 64*256
    int o = i >> 8;
    float v = (o < OCH) ? Wf[i] : 0.f;
    _Float16 h = (_Float16)v;
    Wfh[i] = h;
    Wfl[i] = (_Float16)(v - (float)h);
}

// ---------- KT: x [b][c][pix] fp32 -> xTh/xTl [b][pix][c] f16 planes ----------
// 64c x 64pix tile via LDS [64][65] u32 (h|l packed); both phases 2-way banks (free).
__global__ __launch_bounds__(256) void kT_split(const float* __restrict__ x,
                                                _Float16* __restrict__ xTh,
                                                _Float16* __restrict__ xTl) {
    int b = blockIdx.z, c0 = blockIdx.y * 64, p0 = blockIdx.x * 64;
    __shared__ uint tl[64 * 65];
    int t = threadIdx.x;
    int cr = t >> 2, pq = t & 3;              // phase 1: row c0+cr, pixels pq*16..+15
    const float* xp = x + ((size_t)(b * CCH + c0 + cr)) * NPIX + p0 + pq * 16;
#pragma unroll
    for (int g = 0; g < 4; ++g) {
        float4 v = *(const float4*)(xp + g * 4);
        float vv[4] = {v.x, v.y, v.z, v.w};
#pragma unroll
        for (int j = 0; j < 4; ++j)
            tl[cr * 65 + pq * 16 + g * 4 + j] = packhl(vv[j]);
    }
    __syncthreads();
    int pr = t >> 2, cq = t & 3;              // phase 2: pixel p0+pr, c range cq*16..+15
    union { ushort u[16]; uint4 q[2]; } H, L;
#pragma unroll
    for (int j = 0; j < 16; ++j) {
        uint u = tl[(cq * 16 + j) * 65 + pr];
        H.u[j] = (ushort)(u & 0xffff);
        L.u[j] = (ushort)(u >> 16);
    }
    size_t ob = ((size_t)b * NPIX + p0 + pr) * CCH + c0 + cq * 16;
    *(uint4*)(xTh + ob)     = H.q[0];
    *(uint4*)(xTh + ob + 8) = H.q[1];
    *(uint4*)(xTl + ob)     = L.q[0];
    *(uint4*)(xTl + ob + 8) = L.q[1];
}

// ---------- K12: fused F-GEMM (streaming, barrier-free) + S-partial GEMM ----------
__global__ __launch_bounds__(256, 4) void k12_mfma(const float* __restrict__ x,
                                                   const _Float16* __restrict__ Wfh,
                                                   const _Float16* __restrict__ Wfl,
                                                   const _Float16* __restrict__ xTh,
                                                   const _Float16* __restrict__ xTl,
                                                   float* __restrict__ Spart) {
    int b  = blockIdx.y;
    int ks = blockIdx.x;        // 0..255
    int p0 = ks * KC2;
    int t  = threadIdx.x;
    int w = t >> 6, lane = t & 63, r16 = lane & 15, kg = lane >> 4;
    __shared__ float Ft[4][16 * 68];

    // ---- stage 1: F[o16(w), pix64] = Wf * x, operands streamed from split planes ----
    f32x4 acc[4];
#pragma unroll
    for (int nt = 0; nt < 4; ++nt) acc[nt] = {0.f, 0.f, 0.f, 0.f};

    const _Float16* Ahp = Wfh + (w * 16 + r16) * CCH + kg * 8;
    const _Float16* Alp = Wfl + (w * 16 + r16) * CCH + kg * 8;
    const _Float16* Bhp = xTh + ((size_t)b * NPIX + p0 + r16) * CCH + kg * 8;
    const _Float16* Blp = xTl + ((size_t)b * NPIX + p0 + r16) * CCH + kg * 8;

#pragma unroll
    for (int s = 0; s < 8; ++s) {
        f16x8 Ah = *(const f16x8*)(Ahp + s * 32);
        f16x8 Al = *(const f16x8*)(Alp + s * 32);
#pragma unroll
        for (int nt = 0; nt < 4; ++nt) {
            f16x8 Bh = *(const f16x8*)(Bhp + (size_t)(nt * 16) * CCH + s * 32);
            f16x8 Bl = *(const f16x8*)(Blp + (size_t)(nt * 16) * CCH + s * 32);
            acc[nt] = __builtin_amdgcn_mfma_f32_16x16x32_f16(Ah, Bh, acc[nt], 0, 0, 0);
            acc[nt] = __builtin_amdgcn_mfma_f32_16x16x32_f16(Ah, Bl, acc[nt], 0, 0, 0);
            acc[nt] = __builtin_amdgcn_mfma_f32_16x16x32_f16(Al, Bh, acc[nt], 0, 0, 0);
        }
    }

    // ---- handoff: per-wave F transpose (C/D lane=pix -> A-frag lane=o) ----
    float* ft = Ft[w];
#pragma unroll
    for (int nt = 0; nt < 4; ++nt)
#pragma unroll
        for (int r = 0; r < 4; ++r)
            ft[(kg * 4 + r) * 68 + nt * 16 + r16] = acc[nt][r];
    __syncthreads();

    f16x8 Ah0, Al0, Ah1, Al1;
    {
        const float* fr = ft + r16 * 68;
        cvt_split(*(const float4*)(fr + kg * 8), *(const float4*)(fr + kg * 8 + 4), Ah0, Al0);
        cvt_split(*(const float4*)(fr + 32 + kg * 8), *(const float4*)(fr + 32 + kg * 8 + 4), Ah1, Al1);
    }

    // ---- stage 2: Spart[o16(w), c256] = F * x^T over the same 64 pixels ----
    const float* Bb = x + ((size_t)b * CCH) * NPIX + p0 + kg * 8;
#pragma unroll
    for (int half = 0; half < 2; ++half) {
        f32x4 sacc[8];
#pragma unroll
        for (int i = 0; i < 8; ++i) sacc[i] = {0.f, 0.f, 0.f, 0.f};
#pragma unroll
        for (int ct = 0; ct < 8; ++ct) {
            int c = (half * 8 + ct) * 16 + r16;
            const float* bp = Bb + (size_t)c * NPIX;
            f16x8 bh, bl;
            cvt_split(*(const float4*)bp, *(const float4*)(bp + 4), bh, bl);
            sacc[ct] = __builtin_amdgcn_mfma_f32_16x16x32_f16(Ah0, bh, sacc[ct], 0, 0, 0);
            sacc[ct] = __builtin_amdgcn_mfma_f32_16x16x32_f16(Ah0, bl, sacc[ct], 0, 0, 0);
            sacc[ct] = __builtin_amdgcn_mfma_f32_16x16x32_f16(Al0, bh, sacc[ct], 0, 0, 0);
            cvt_split(*(const float4*)(bp + 32), *(const float4*)(bp + 36), bh, bl);
            sacc[ct] = __builtin_amdgcn_mfma_f32_16x16x32_f16(Ah1, bh, sacc[ct], 0, 0, 0);
            sacc[ct] = __builtin_amdgcn_mfma_f32_16x16x32_f16(Ah1, bl, sacc[ct], 0, 0, 0);
            sacc[ct] = __builtin_amdgcn_mfma_f32_16x16x32_f16(Al1, bh, sacc[ct], 0, 0, 0);
        }
        float* Sp = Spart + (((size_t)ks * BATCH + b) * 64 + w * 16 + kg * 4) * 256
                  + half * 128 + r16;
#pragma unroll
        for (int ct = 0; ct < 8; ++ct)
#pragma unroll
            for (int r = 0; r < 4; ++r)
                Sp[(size_t)r * 256 + ct * 16] = sacc[ct][r];
    }
}

// ---------- K2r: reduce partials (4-way split) + softmax over c ----------
__global__ __launch_bounds__(1024) void k2r_softmax(const float* __restrict__ Spart,
                                                    float* __restrict__ S) {
    int row = blockIdx.x;   // 0..199
    int b = row / OCH, o = row % OCH;
    int tid = threadIdx.x;
    int c = tid & 255, g = tid >> 8;
    __shared__ float part[4][CCH];
    __shared__ float red[8];
    float v = 0.f;
    const size_t ksStride = (size_t)BATCH * 64 * 256;
    const float* p = Spart + ((size_t)(g * (NSPLIT2 / 4)) * BATCH + b) * 64 * 256
                   + (size_t)o * 256 + c;
#pragma unroll 8
    for (int ks = 0; ks < NSPLIT2 / 4; ++ks)
        v += p[ks * ksStride];
    part[g][c] = v;
    __syncthreads();
    float vv = 0.f, e = 0.f, m;
    if (tid < 256) {
        vv = part[0][c] + part[1][c] + part[2][c] + part[3][c];
        m = vv;
#pragma unroll
        for (int off = 32; off > 0; off >>= 1) m = fmaxf(m, __shfl_xor(m, off, 64));
        if ((tid & 63) == 0) red[tid >> 6] = m;
    }
    __syncthreads();
    if (tid < 256) {
        m = fmaxf(fmaxf(red[0], red[1]), fmaxf(red[2], red[3]));
        e = expf(vv - m);
        float s = e;
#pragma unroll
        for (int off = 32; off > 0; off >>= 1) s += __shfl_xor(s, off, 64);
        if ((tid & 63) == 0) red[4 + (tid >> 6)] = s;
    }
    __syncthreads();
    if (tid < 256) {
        float tot = red[4] + red[5] + red[6] + red[7];
        S[(size_t)row * CCH + c] = e / tot;
    }
}

// ---------- K3: Mt[b*O+o, d] = sum_c Wbeta[d,c] * S[b*O+o, c] ----------
__global__ __launch_bounds__(256) void k3_M(const float* __restrict__ Wbeta,
                                            const float* __restrict__ S,
                                            float* __restrict__ Mt) {
    int row = blockIdx.x;
    int d = threadIdx.x;
    const float* srow = S + (size_t)row * CCH;
    const float4* wb = (const float4*)(Wbeta + (size_t)d * CCH);
    float acc = 0.f;
#pragma unroll 4
    for (int cg = 0; cg < CCH / 4; ++cg) {
        float4 w = wb[cg];
        float4 s = *(const float4*)(srow + cg * 4);
        acc += w.x * s.x + w.y * s.y + w.z * s.z + w.w * s.w;
    }
    Mt[(size_t)row * CCH + d] = acc;
}

// ---------- K3b: G'[b,d,c] = sum_o Mt[b,o,d]*Wf[o,c] + (d==c), split f16 planes ----------
__global__ __launch_bounds__(256) void k3b_G(const float* __restrict__ Mt,
                                             const float* __restrict__ Wf,
                                             _Float16* __restrict__ Gh,
                                             _Float16* __restrict__ Gl) {
    int bd = blockIdx.x;        // b*256 + d
    int b = bd >> 8, d = bd & 255;
    int c = threadIdx.x;
    float acc = (d == c) ? 1.f : 0.f;      // residual folded into G
    const float* mp = Mt + ((size_t)b * OCH) * CCH + d;
#pragma unroll 5
    for (int o = 0; o < OCH; ++o)
        acc = fmaf(mp[(size_t)o * CCH], Wf[o * CCH + c], acc);
    _Float16 h = (_Float16)acc;
    Gh[(size_t)bd * CCH + c] = h;
    Gl[(size_t)bd * CCH + c] = (_Float16)(acc - (float)h);
}

// ---------- K4: out[b,d,pix] = sum_c G'[b,d,c] * x[b,c,pix]  (pure streaming GEMM) ----------
// No LDS, no barriers: A from G' planes (L2-hot), B from xT planes (HBM stream).
__global__ __launch_bounds__(256, 3) void k4_mfma(const _Float16* __restrict__ xTh,
                                                  const _Float16* __restrict__ xTl,
                                                  const _Float16* __restrict__ Gh,
                                                  const _Float16* __restrict__ Gl,
                                                  float* __restrict__ out) {
    int b  = blockIdx.y;
    int ks = blockIdx.x;
    int p0 = ks * KC2;
    int t  = threadIdx.x;
    int w = t >> 6, lane = t & 63, r16 = lane & 15, kg = lane >> 4;

    f32x4 acc[4][4];
#pragma unroll
    for (int mt = 0; mt < 4; ++mt)
#pragma unroll
        for (int nt = 0; nt < 4; ++nt) acc[mt][nt] = {0.f, 0.f, 0.f, 0.f};

    const _Float16* GhB = Gh + ((size_t)b * 256 + w * 64 + r16) * CCH + kg * 8;
    const _Float16* GlB = Gl + ((size_t)b * 256 + w * 64 + r16) * CCH + kg * 8;
    const _Float16* BhB = xTh + ((size_t)b * NPIX + p0 + r16) * CCH + kg * 8;
    const _Float16* BlB = xTl + ((size_t)b * NPIX + p0 + r16) * CCH + kg * 8;

#pragma unroll
    for (int s = 0; s < 8; ++s) {
        f16x8 Ah[4], Al[4], Bh[4], Bl[4];
#pragma unroll
        for (int mt = 0; mt < 4; ++mt) {
            Ah[mt] = *(const f16x8*)(GhB + (size_t)(mt * 16) * CCH + s * 32);
            Al[mt] = *(const f16x8*)(GlB + (size_t)(mt * 16) * CCH + s * 32);
        }
#pragma unroll
        for (int nt = 0; nt < 4; ++nt) {
            Bh[nt] = *(const f16x8*)(BhB + (size_t)(nt * 16) * CCH + s * 32);
            Bl[nt] = *(const f16x8*)(BlB + (size_t)(nt * 16) * CCH + s * 32);
        }
#pragma unroll
        for (int mt = 0; mt < 4; ++mt)
#pragma unroll
            for (int nt = 0; nt < 4; ++nt) {
                acc[mt][nt] = __builtin_amdgcn_mfma_f32_16x16x32_f16(Ah[mt], Bh[nt], acc[mt][nt], 0, 0, 0);
                acc[mt][nt] = __builtin_amdgcn_mfma_f32_16x16x32_f16(Ah[mt], Bl[nt], acc[mt][nt], 0, 0, 0);
                acc[mt][nt] = __builtin_amdgcn_mfma_f32_16x16x32_f16(Al[mt], Bh[nt], acc[mt][nt], 0, 0, 0);
            }
    }

    float* op = out + ((size_t)b * CCH + w * 64 + kg * 4) * NPIX + p0 + r16;
#pragma unroll
    for (int mt = 0; mt < 4; ++mt)
#pragma unroll
        for (int nt = 0; nt < 4; ++nt)
#pragma unroll
            for (int r = 0; r < 4; ++r)
                __builtin_nontemporal_store(acc[mt][nt][r],
                                            &op[(size_t)(mt * 16 + r) * NPIX + nt * 16]);
}

extern "C" void kernel_launch(void* const* d_in, const int* in_sizes, int n_in,
                              void* d_out, int out_size, void* d_ws, size_t ws_size,
                              hipStream_t stream) {
    const float* x     = (const float*)d_in[0];   // [4,256,128,128]
    const float* Wf    = (const float*)d_in[1];   // [50,256]
    const float* Wbeta = (const float*)d_in[2];   // [256,256]
    float* out = (float*)d_out;

    // ws layout: xTh [B*NPIX*CCH f16] | xTl | Wfh [64*256 f16] | Wfl | S [BO*C f32]
    //          | Mt [BO*C f32] | Gh [B*256*256 f16] | Gl      (~69 MB, ws ~268 MB)
    const size_t PLANE = (size_t)BATCH * NPIX * CCH;
    _Float16* xTh = (_Float16*)d_ws;
    _Float16* xTl = xTh + PLANE;
    _Float16* Wfh = xTl + PLANE;
    _Float16* Wfl = Wfh + 64 * CCH;
    float*    S   = (float*)(Wfl + 64 * CCH);
    float*    Mt  = S + (size_t)BO * CCH;
    _Float16* Gh  = (_Float16*)(Mt + (size_t)BO * CCH);
    _Float16* Gl  = Gh + (size_t)BATCH * 256 * CCH;
    // S-partials live in d_out (free until K4): 256*4*64*256 == out_size
    float* Spart = out;

    k0_split<<<dim3(64), dim3(256), 0, stream>>>(Wf, Wfh, Wfl);
    kT_split<<<dim3(NPIX / 64, CCH / 64, BATCH), dim3(256), 0, stream>>>(x, xTh, xTl);
    k12_mfma<<<dim3(NSPLIT2, BATCH), dim3(256), 0, stream>>>(x, Wfh, Wfl, xTh, xTl, Spart);
    k2r_softmax<<<dim3(BO), dim3(1024), 0, stream>>>(Spart, S);
    k3_M<<<dim3(BO), dim3(256), 0, stream>>>(Wbeta, S, Mt);
    k3b_G<<<dim3(BATCH * 256), dim3(256), 0, stream>>>(Mt, Wf, Gh, Gl);
    k4_mfma<<<dim3(NSPLIT2, BATCH), dim3(256), 0, stream>>>(xTh, xTl, Gh, Gl, out);
}